// Round 2
// baseline (344.207 us; speedup 1.0000x reference)
//
#include <hip/hip_runtime.h>

#define B_ 1024
#define S_ 256
#define D_ 128
#define K_ 26

// ---------------- Kernel 1: emissions E[b][t][k] = dot(X[b][t], W[k]) ----------------
// grid 4096: b = bid/4, row-quarter r0 = (bid%4)*64. 256 threads = 4 waves.
// Wave g computes k-group g: offsets {0,7,14,20}, sizes {7,7,6,6}.
__global__ __launch_bounds__(256, 2) void emis_kernel(
    const float* __restrict__ X, const float* __restrict__ W, float* __restrict__ E)
{
  __shared__ float xt[64][132];   // +4 pad: bank = (4*row + col)%32, conflict-free per 8 lanes
  const int tid = threadIdx.x;
  const int b   = blockIdx.x >> 2;
  const int r0  = (blockIdx.x & 3) << 6;

  {
    const float4* Xs = reinterpret_cast<const float4*>(X + ((size_t)b * S_ + r0) * D_);
#pragma unroll
    for (int it = 0; it < 8; ++it) {
      int i = it * 256 + tid;             // float4 index, 0..2047
      float4 v = Xs[i];
      int row = i >> 5, col = (i & 31) << 2;
      *reinterpret_cast<float4*>(&xt[row][col]) = v;
    }
  }
  __syncthreads();

  const int l = tid & 63;                               // row within tile
  const int g = __builtin_amdgcn_readfirstlane(tid >> 6);  // uniform k-group
  const int k0 = (g < 2) ? 7 * g : 6 * g + 2;           // 0,7,14,20
  const int kn = (g < 2) ? 7 : 6;

  float acc[7][4];
#pragma unroll
  for (int kk = 0; kk < 7; ++kk)
#pragma unroll
    for (int c = 0; c < 4; ++c) acc[kk][c] = 0.f;

#pragma unroll
  for (int dc = 0; dc < 16; ++dc) {
    float4 a0 = *reinterpret_cast<const float4*>(&xt[l][dc * 8]);
    float4 a1 = *reinterpret_cast<const float4*>(&xt[l][dc * 8 + 4]);
    float xv[8] = {a0.x, a0.y, a0.z, a0.w, a1.x, a1.y, a1.z, a1.w};
#pragma unroll
    for (int kk = 0; kk < 7; ++kk) {
      int k = k0 + kk; k = (k > K_ - 1) ? (K_ - 1) : k;   // clamp (avoids OOB, result unused)
      const float* wr = W + k * D_ + dc * 8;              // wave-uniform address -> s_load
#pragma unroll
      for (int dd = 0; dd < 8; ++dd)
        acc[kk][dd & 3] = fmaf(xv[dd], wr[dd], acc[kk][dd & 3]);
    }
  }

  float* eb = E + ((size_t)b * S_ + r0 + l) * K_ + k0;
#pragma unroll
  for (int kk = 0; kk < 7; ++kk)
    if (kk < kn)
      eb[kk] = (acc[kk][0] + acc[kk][1]) + (acc[kk][2] + acc[kk][3]);
}

// ---------------- Kernel 2: Viterbi recurrence + backtrack, one wave per chain --------
__global__ __launch_bounds__(64, 1) void viterbi_kernel(
    const float* __restrict__ E, const float* __restrict__ Tr, int* __restrict__ out)
{
  __shared__ __align__(16) float e_lds[S_ * K_];   // 26624 B
  __shared__ unsigned char bp[K_][260];            // bp[j][t], pad 260 -> conflict-free
  __shared__ unsigned char spec[K_][132];          // speculative lower-half paths
  __shared__ int path_s[S_];

  const int lane = threadIdx.x;
  const int j    = lane & 31;          // column (state), valid < 26
  const int h    = lane >> 5;          // i-range half: h=0 -> i in [0,13), h=1 -> [13,26)
  const int jc   = (j < K_) ? j : (K_ - 1);
  const int b    = blockIdx.x;

  // stage E[b] (1664 float4)
  {
    const float4* src = reinterpret_cast<const float4*>(E + (size_t)b * (S_ * K_));
    float4* dst = reinterpret_cast<float4*>(e_lds);
#pragma unroll
    for (int it = 0; it < 26; ++it) dst[it * 64 + lane] = src[it * 64 + lane];
  }

  // per-lane transition slice: tch[i] = Tr[i + 13*h][jc]
  float tch[13];
#pragma unroll
  for (int i = 0; i < 13; ++i) tch[i] = Tr[(i + 13 * h) * K_ + jc];

  __syncthreads();

  float delta = e_lds[jc];             // t = 0
  const int srcbase = 13 * h;

  for (int t = 1; t < S_; ++t) {
    float ev = e_lds[t * K_ + jc];
    float v[13]; int id[13];
#pragma unroll
    for (int i = 0; i < 13; ++i) {
      v[i]  = __shfl(delta, srcbase + i, 64) + tch[i];   // bpermute broadcast
      id[i] = srcbase + i;
    }
    // ordered tournament (keep LEFT = lower index on ties -> first-max like jnp.argmax)
#pragma unroll
    for (int w = 1; w < 16; w <<= 1) {
#pragma unroll
      for (int i = 0; i + w < 13; i += 2 * w) {
        bool gt = v[i + w] > v[i];
        v[i]  = gt ? v[i + w] : v[i];
        id[i] = gt ? id[i + w] : id[i];
      }
    }
    // cross-half merge: lower-i half must be the tie-preferred side
    float ov = __shfl_xor(v[0], 32, 64);
    int   oi = __shfl_xor(id[0], 32, 64);
    float lv = (h == 0) ? v[0] : ov;   int li = (h == 0) ? id[0] : oi;
    float hv = (h == 0) ? ov   : v[0]; int hi_ = (h == 0) ? oi   : id[0];
    bool gt = hv > lv;
    float best = gt ? hv : lv;
    int   bpi  = gt ? hi_ : li;
    if (h == 0 && j < K_) bp[j][t] = (unsigned char)bpi;
    delta = best + ev;                 // same op order as reference (max + e)
  }

  // final first-argmax over delta[0..25]
  float bf = __shfl(delta, 0, 64); int last = 0;
#pragma unroll
  for (int i = 1; i < K_; ++i) {
    float s = __shfl(delta, i, 64);
    bool g = s > bf;
    bf = g ? s : bf;
    last = g ? i : last;
  }

  __syncthreads();

  // backtrack: real chain (lane 63) t=255..129 concurrently with 26 speculative
  // chains (lanes 0..25) covering t=128..1 for every possible state@128.
  {
    int c = (lane < K_) ? lane : last;
    for (int k = 0; k < 128; ++k) {
      int t = (lane < K_) ? (128 - k) : (255 - k);
      bool act = (lane < K_) || (lane == 63 && k <= 126);
      if (act) {
        c = bp[c][t];
        if (lane < K_) spec[lane][t - 1] = (unsigned char)c;
        else if (t >= 129) path_s[t - 1] = c;   // covers 128..254
      }
    }
  }
  __syncthreads();

  {
    int sstar = path_s[128];           // realized state at t=128
#pragma unroll
    for (int q = 0; q < 2; ++q) {
      int t = q * 64 + lane;
      path_s[t] = (int)spec[sstar][t];
    }
    if (lane == 0) path_s[S_ - 1] = last;
  }
  __syncthreads();

  int* o = out + (size_t)b * S_;
#pragma unroll
  for (int q = 0; q < 4; ++q) o[q * 64 + lane] = path_s[q * 64 + lane];
}

extern "C" void kernel_launch(void* const* d_in, const int* in_sizes, int n_in,
                              void* d_out, int out_size, void* d_ws, size_t ws_size,
                              hipStream_t stream) {
  (void)in_sizes; (void)n_in; (void)out_size; (void)ws_size;
  const float* X  = (const float*)d_in[0];
  const float* W  = (const float*)d_in[1];
  const float* Tr = (const float*)d_in[2];
  float* E = (float*)d_ws;             // needs B*S*K*4 = 27,262,976 B of scratch
  int* outp = (int*)d_out;

  emis_kernel<<<B_ * 4, 256, 0, stream>>>(X, W, E);
  viterbi_kernel<<<B_, 64, 0, stream>>>(E, Tr, outp);
}